// Round 1
// baseline (850.111 us; speedup 1.0000x reference)
//
#include <hip/hip_runtime.h>
#include <hip/hip_bf16.h>

typedef __bf16 bf16;
typedef __attribute__((ext_vector_type(8))) __bf16 bf16x8;
typedef __attribute__((ext_vector_type(4))) __bf16 bf16x4;
typedef __attribute__((ext_vector_type(4))) float floatx4;

#define E_DIM 4096
#define H_DIM 32
#define D_DIM 128
#define M_DIM 256
#define B_DIM 8
#define N_DIM 256

// async global->LDS, 16B per lane, lds dest = base + lane*16 (wave-uniform base)
#define GLD_LDS(g, l) __builtin_amdgcn_global_load_lds( \
    (const __attribute__((address_space(1))) unsigned int*)(g), \
    (__attribute__((address_space(3))) unsigned int*)(l), 16, 0, 0)

__device__ __forceinline__ float wave_sum(float v) {
#pragma unroll
  for (int o = 32; o; o >>= 1) v += __shfl_xor(v, o);
  return v;
}
__device__ __forceinline__ float wave_max(float v) {
#pragma unroll
  for (int o = 32; o; o >>= 1) v = fmaxf(v, __shfl_xor(v, o));
  return v;
}

// ---------------- fp32 -> bf16 weight conversion ----------------
__global__ __launch_bounds__(256) void cvt_kernel(const float* __restrict__ src,
                                                  bf16* __restrict__ dst, long n) {
  long i = ((long)blockIdx.x * 256 + threadIdx.x) * 8;
  if (i >= n) return;
  float4 a = *(const float4*)(src + i);
  float4 b = *(const float4*)(src + i + 4);
  bf16x8 p;
  p[0] = (bf16)a.x; p[1] = (bf16)a.y; p[2] = (bf16)a.z; p[3] = (bf16)a.w;
  p[4] = (bf16)b.x; p[5] = (bf16)b.y; p[6] = (bf16)b.z; p[7] = (bf16)b.w;
  *(bf16x8*)(dst + i) = p;
}

// ---------------- LayerNorm(x) -> kv (bf16), kin = kv + pos (bf16) ----------------
__global__ __launch_bounds__(256) void ln_x_kernel(const float* __restrict__ x,
                                                   const float* __restrict__ w,
                                                   const float* __restrict__ bvec,
                                                   const float* __restrict__ pos,
                                                   bf16* __restrict__ kv,
                                                   bf16* __restrict__ kin) {
  const int row = blockIdx.x;          // b*256 + n
  const int n = row & (N_DIM - 1);
  const int tid = threadIdx.x, wid = tid >> 6, lane = tid & 63;
  const float* xr = x + (size_t)row * E_DIM;
  float4 v[4];
  float s1 = 0.f, s2 = 0.f;
#pragma unroll
  for (int j = 0; j < 4; ++j) {
    v[j] = *(const float4*)(xr + j * 1024 + tid * 4);
    s1 += v[j].x + v[j].y + v[j].z + v[j].w;
    s2 += v[j].x * v[j].x + v[j].y * v[j].y + v[j].z * v[j].z + v[j].w * v[j].w;
  }
  s1 = wave_sum(s1); s2 = wave_sum(s2);
  __shared__ float red[8];
  if (lane == 0) { red[wid] = s1; red[wid + 4] = s2; }
  __syncthreads();
  s1 = red[0] + red[1] + red[2] + red[3];
  s2 = red[4] + red[5] + red[6] + red[7];
  const float mean = s1 * (1.f / E_DIM);
  const float var = s2 * (1.f / E_DIM) - mean * mean;
  const float rs = rsqrtf(var + 1e-5f);
#pragma unroll
  for (int j = 0; j < 4; ++j) {
    const int idx = j * 1024 + tid * 4;
    float4 wv = *(const float4*)(w + idx);
    float4 bv = *(const float4*)(bvec + idx);
    float4 pv = *(const float4*)(pos + (size_t)n * E_DIM + idx);
    float y0 = (v[j].x - mean) * rs * wv.x + bv.x;
    float y1 = (v[j].y - mean) * rs * wv.y + bv.y;
    float y2 = (v[j].z - mean) * rs * wv.z + bv.z;
    float y3 = (v[j].w - mean) * rs * wv.w + bv.w;
    bf16x4 a; a[0] = (bf16)y0; a[1] = (bf16)y1; a[2] = (bf16)y2; a[3] = (bf16)y3;
    *(bf16x4*)(kv + (size_t)row * E_DIM + idx) = a;
    bf16x4 c; c[0] = (bf16)(y0 + pv.x); c[1] = (bf16)(y1 + pv.y);
    c[2] = (bf16)(y2 + pv.z); c[3] = (bf16)(y3 + pv.w);
    *(bf16x4*)(kin + (size_t)row * E_DIM + idx) = c;
  }
}

// ---------------- LayerNorm(query) + pos -> qin (bf16) ----------------
__global__ __launch_bounds__(256) void ln_q_kernel(const float* __restrict__ q,
                                                   const float* __restrict__ w,
                                                   const float* __restrict__ bvec,
                                                   const float* __restrict__ pos,
                                                   bf16* __restrict__ qin) {
  const int row = blockIdx.x;  // m
  const int tid = threadIdx.x, wid = tid >> 6, lane = tid & 63;
  const float* xr = q + (size_t)row * E_DIM;
  float4 v[4];
  float s1 = 0.f, s2 = 0.f;
#pragma unroll
  for (int j = 0; j < 4; ++j) {
    v[j] = *(const float4*)(xr + j * 1024 + tid * 4);
    s1 += v[j].x + v[j].y + v[j].z + v[j].w;
    s2 += v[j].x * v[j].x + v[j].y * v[j].y + v[j].z * v[j].z + v[j].w * v[j].w;
  }
  s1 = wave_sum(s1); s2 = wave_sum(s2);
  __shared__ float red[8];
  if (lane == 0) { red[wid] = s1; red[wid + 4] = s2; }
  __syncthreads();
  s1 = red[0] + red[1] + red[2] + red[3];
  s2 = red[4] + red[5] + red[6] + red[7];
  const float mean = s1 * (1.f / E_DIM);
  const float var = s2 * (1.f / E_DIM) - mean * mean;
  const float rs = rsqrtf(var + 1e-5f);
#pragma unroll
  for (int j = 0; j < 4; ++j) {
    const int idx = j * 1024 + tid * 4;
    float4 wv = *(const float4*)(w + idx);
    float4 bv = *(const float4*)(bvec + idx);
    float4 pv = *(const float4*)(pos + (size_t)row * E_DIM + idx);
    bf16x4 a;
    a[0] = (bf16)((v[j].x - mean) * rs * wv.x + bv.x + pv.x);
    a[1] = (bf16)((v[j].y - mean) * rs * wv.y + bv.y + pv.y);
    a[2] = (bf16)((v[j].z - mean) * rs * wv.z + bv.z + pv.z);
    a[3] = (bf16)((v[j].w - mean) * rs * wv.w + bv.w + pv.w);
    *(bf16x4*)(qin + (size_t)row * E_DIM + idx) = a;
  }
}

// ---------------- m97-style BT GEMM: C[m,n] = sum_k A[m,k]*B[n,k] ----------------
// MODE 0: +bias, bf16 store (q,k proj)      MODE 1: +bias, store V^T (b,h,d,n)
// MODE 2: batched z=(b,h), *scale, f32      MODE 3: batched z, bf16 -> o(b,m,h*128+d)
// MODE 4: +bias, f32 store (final out)
template <int MODE>
__global__ __launch_bounds__(256, 2)
void gemm_bt(const bf16* __restrict__ Abase, const bf16* __restrict__ Bbase,
             const float* __restrict__ bias, float* __restrict__ Cf,
             bf16* __restrict__ Cb, int M, int N, int K, int lda, int ldb, int ldc,
             float scale) {
  __shared__ __align__(16) bf16 As[4096];
  __shared__ __align__(16) bf16 Bs[4096];
  const int tid = threadIdx.x;
  const int wid = tid >> 6;
  const int lane = tid & 63;

  const bf16* A = Abase;
  const bf16* B = Bbase;
  int zb = 0, zh = 0;
  if constexpr (MODE == 2) {
    int z = blockIdx.z; zb = z >> 5; zh = z & 31;
    A += zh * D_DIM;
    B += ((size_t)zb * N_DIM) * E_DIM + zh * D_DIM;
  } else if constexpr (MODE == 3) {
    int z = blockIdx.z; zb = z >> 5; zh = z & 31;
    A += (size_t)z * M_DIM * 512;   // probs: 512-ushort row stride (in-place in score rows)
    B += (size_t)z * D_DIM * N_DIM; // vt batch
  }

  const bf16* Arow = A + (size_t)(blockIdx.y * 128) * lda;
  const bf16* Brow = B + (size_t)(blockIdx.x * 128) * ldb;

  const int s0 = wid * 2;
  const int srow = lane >> 2;          // 0..15 within segment
  const int skoff = (lane & 3) * 8;    // k offset in elements

  floatx4 acc[4][4];
#pragma unroll
  for (int i = 0; i < 4; ++i)
#pragma unroll
    for (int j = 0; j < 4; ++j) acc[i][j] = (floatx4){0.f, 0.f, 0.f, 0.f};

  const int rA = (wid >> 1) * 64 + (lane & 15);
  const int rB = (wid & 1) * 64 + (lane & 15);
  const int q16 = (lane >> 4) * 8;

  const int kTiles = K >> 5;
  for (int kt = 0; kt < kTiles; ++kt) {
    const int k0 = kt << 5;
#pragma unroll
    for (int c = 0; c < 2; ++c) {
      const int s = s0 + c;
      const int row = s * 16 + srow;
      GLD_LDS(Arow + (size_t)row * lda + k0 + skoff, As + s * 512);
      GLD_LDS(Brow + (size_t)row * ldb + k0 + skoff, Bs + s * 512);
    }
    asm volatile("s_waitcnt vmcnt(0)" ::: "memory");
    __syncthreads();

    bf16x8 af[4], bfr[4];
#pragma unroll
    for (int t = 0; t < 4; ++t) {
      af[t] = *(const bf16x8*)(As + (rA + t * 16) * 32 + q16);
      bfr[t] = *(const bf16x8*)(Bs + (rB + t * 16) * 32 + q16);
    }
#pragma unroll
    for (int tr = 0; tr < 4; ++tr)
#pragma unroll
      for (int tc = 0; tc < 4; ++tc)
        acc[tr][tc] = __builtin_amdgcn_mfma_f32_16x16x32_bf16(af[tr], bfr[tc],
                                                              acc[tr][tc], 0, 0, 0);
    __syncthreads();
  }

  const int mb = blockIdx.y * 128 + (wid >> 1) * 64 + (lane >> 4) * 4;
  const int nb = blockIdx.x * 128 + (wid & 1) * 64 + (lane & 15);
#pragma unroll
  for (int tr = 0; tr < 4; ++tr) {
#pragma unroll
    for (int tc = 0; tc < 4; ++tc) {
      const int row0 = mb + tr * 16;
      const int col = nb + tc * 16;
      floatx4 a = acc[tr][tc];
      if constexpr (MODE == 0) {
        const float bb = bias[col];
#pragma unroll
        for (int r = 0; r < 4; ++r)
          Cb[(size_t)(row0 + r) * ldc + col] = (bf16)(a[0 + r] + bb);
      } else if constexpr (MODE == 1) {
        const float bb = bias[col];
        const int h = col >> 7, d = col & 127;
        const int b_ = row0 >> 8, n_ = row0 & 255;
        bf16x4 p;
#pragma unroll
        for (int r = 0; r < 4; ++r) p[r] = (bf16)(a[r] + bb);
        *(bf16x4*)(Cb + ((size_t)((b_ * H_DIM + h) * D_DIM + d)) * N_DIM + n_) = p;
      } else if constexpr (MODE == 2) {
#pragma unroll
        for (int r = 0; r < 4; ++r)
          Cf[(size_t)blockIdx.z * (M_DIM * N_DIM) + (size_t)(row0 + r) * ldc + col] =
              a[r] * scale;
      } else if constexpr (MODE == 3) {
#pragma unroll
        for (int r = 0; r < 4; ++r)
          Cb[(size_t)zb * M_DIM * E_DIM + (size_t)(row0 + r) * E_DIM + zh * D_DIM + col] =
              (bf16)a[r];
      } else {
        const float bb = bias[col];
#pragma unroll
        for (int r = 0; r < 4; ++r)
          Cf[(size_t)(row0 + r) * ldc + col] = a[r] + bb;
      }
    }
  }
}

// ---------------- softmax over N per (b,h,m) + head-mean; probs bf16 in place ----------------
__global__ __launch_bounds__(256) void softmax_mean_kernel(float* __restrict__ scores,
                                                           float* __restrict__ out_mean) {
  const int bm = blockIdx.x;  // b*256 + m
  const int b = bm >> 8, m = bm & 255;
  const int wid = threadIdx.x >> 6, lane = threadIdx.x & 63;
  float a0 = 0.f, a1 = 0.f, a2 = 0.f, a3 = 0.f;
  for (int j = 0; j < 8; ++j) {
    const int h = wid * 8 + j;
    float* row = scores + ((size_t)((b * H_DIM + h) * M_DIM + m)) * N_DIM;
    float4 v = *(const float4*)(row + lane * 4);
    float mx = fmaxf(fmaxf(v.x, v.y), fmaxf(v.z, v.w));
    mx = wave_max(mx);
    v.x = __expf(v.x - mx); v.y = __expf(v.y - mx);
    v.z = __expf(v.z - mx); v.w = __expf(v.w - mx);
    const float s = wave_sum(v.x + v.y + v.z + v.w);
    const float inv = 1.f / s;
    v.x *= inv; v.y *= inv; v.z *= inv; v.w *= inv;
    a0 += v.x; a1 += v.y; a2 += v.z; a3 += v.w;
    bf16x4 p; p[0] = (bf16)v.x; p[1] = (bf16)v.y; p[2] = (bf16)v.z; p[3] = (bf16)v.w;
    *(bf16x4*)((bf16*)row + lane * 4) = p;  // in-place: first 512B of the 1KB row
  }
  __shared__ float red[4][256];
  *(float4*)&red[wid][lane * 4] = make_float4(a0, a1, a2, a3);
  __syncthreads();
  if (wid == 0) {
    float4 r0 = *(float4*)&red[0][lane * 4];
    float4 r1 = *(float4*)&red[1][lane * 4];
    float4 r2 = *(float4*)&red[2][lane * 4];
    float4 r3 = *(float4*)&red[3][lane * 4];
    float4 o;
    o.x = (r0.x + r1.x + r2.x + r3.x) * (1.f / H_DIM);
    o.y = (r0.y + r1.y + r2.y + r3.y) * (1.f / H_DIM);
    o.z = (r0.z + r1.z + r2.z + r3.z) * (1.f / H_DIM);
    o.w = (r0.w + r1.w + r2.w + r3.w) * (1.f / H_DIM);
    *(float4*)(out_mean + (size_t)bm * N_DIM + lane * 4) = o;
  }
}

extern "C" void kernel_launch(void* const* d_in, const int* in_sizes, int n_in,
                              void* d_out, int out_size, void* d_ws, size_t ws_size,
                              hipStream_t stream) {
  const float* x = (const float*)d_in[0];
  const float* query = (const float*)d_in[1];
  const float* pos = (const float*)d_in[2];
  const float* ln_q_w = (const float*)d_in[3];
  const float* ln_q_b = (const float*)d_in[4];
  const float* ln_kv_w = (const float*)d_in[5];
  const float* ln_kv_b = (const float*)d_in[6];
  const float* Wqkv_f = (const float*)d_in[7];
  const float* bqkv = (const float*)d_in[8];
  const float* Wout_f = (const float*)d_in[9];
  const float* bout = (const float*)d_in[10];

  char* ws = (char*)d_ws;
  // ws layout (bytes); scores & o alias Wqkv (dead after v-proj). total = 196MB
  bf16* Wqkv = (bf16*)(ws + 0);            // 100,663,296
  bf16* Wout = (bf16*)(ws + 100663296);    // 33,554,432
  bf16* kv   = (bf16*)(ws + 134217728);    // 16,777,216
  bf16* kin  = (bf16*)(ws + 150994944);    // 16,777,216
  bf16* qin  = (bf16*)(ws + 167772160);    //  2,097,152
  bf16* qp   = (bf16*)(ws + 169869312);    //  2,097,152
  bf16* kp   = (bf16*)(ws + 171966464);    // 16,777,216
  bf16* vt   = (bf16*)(ws + 188743680);    // 16,777,216 -> end 205,520,896
  float* scores = (float*)(ws + 0);        // 67,108,864 (alias Wqkv)
  bf16* obuf = (bf16*)(ws + 67108864);     // 16,777,216 (alias Wqkv tail)

  float* out = (float*)d_out;
  float* out2 = out + (size_t)B_DIM * M_DIM * E_DIM;

  cvt_kernel<<<24576, 256, 0, stream>>>(Wqkv_f, Wqkv, 50331648L);
  cvt_kernel<<<8192, 256, 0, stream>>>(Wout_f, Wout, 16777216L);
  ln_x_kernel<<<2048, 256, 0, stream>>>(x, ln_kv_w, ln_kv_b, pos, kv, kin);
  ln_q_kernel<<<256, 256, 0, stream>>>(query, ln_q_w, ln_q_b, pos, qin);

  // q = qin @ Wq^T + bq  (256x4096x4096)
  gemm_bt<0><<<dim3(32, 2, 1), 256, 0, stream>>>(qin, Wqkv, bqkv, nullptr, qp,
                                                 256, 4096, 4096, 4096, 4096, 4096, 1.f);
  // k = kin @ Wk^T + bk  (2048x4096x4096)
  gemm_bt<0><<<dim3(32, 16, 1), 256, 0, stream>>>(kin, Wqkv + (size_t)4096 * 4096,
                                                  bqkv + 4096, nullptr, kp,
                                                  2048, 4096, 4096, 4096, 4096, 4096, 1.f);
  // v = kv @ Wv^T + bv, stored transposed (b,h,d,n)
  gemm_bt<1><<<dim3(32, 16, 1), 256, 0, stream>>>(kv, Wqkv + (size_t)2 * 4096 * 4096,
                                                  bqkv + 8192, nullptr, vt,
                                                  2048, 4096, 4096, 4096, 4096, 4096, 1.f);
  // scores[b,h,m,n] = q.k/sqrt(128)
  gemm_bt<2><<<dim3(2, 2, 256), 256, 0, stream>>>(qp, kp, nullptr, scores, nullptr,
                                                  256, 256, 128, 4096, 4096, 256,
                                                  0.08838834764831845f);
  softmax_mean_kernel<<<2048, 256, 0, stream>>>(scores, out2);
  // o = probs @ v   (per (b,h): 256x128x256), probs rows stride 512 ushorts
  gemm_bt<3><<<dim3(1, 2, 256), 256, 0, stream>>>((const bf16*)scores, vt, nullptr,
                                                  nullptr, obuf,
                                                  256, 128, 256, 512, 256, 4096, 1.f);
  // out = o @ Wout^T + bout (2048x4096x4096), fp32
  gemm_bt<4><<<dim3(32, 16, 1), 256, 0, stream>>>(obuf, Wout, bout, out, nullptr,
                                                  2048, 4096, 4096, 4096, 4096, 4096, 1.f);
}

// Round 2
// 789.452 us; speedup vs baseline: 1.0768x; 1.0768x over previous
//
#include <hip/hip_runtime.h>
#include <hip/hip_bf16.h>

typedef __bf16 bf16;
typedef __attribute__((ext_vector_type(8))) __bf16 bf16x8;
typedef __attribute__((ext_vector_type(4))) __bf16 bf16x4;
typedef __attribute__((ext_vector_type(4))) float floatx4;

#define E_DIM 4096
#define H_DIM 32
#define D_DIM 128
#define M_DIM 256
#define B_DIM 8
#define N_DIM 256

// async global->LDS, 16B per lane, lds dest = base + lane*16 (wave-uniform base)
#define GLD_LDS(g, l) __builtin_amdgcn_global_load_lds( \
    (const __attribute__((address_space(1))) unsigned int*)(g), \
    (__attribute__((address_space(3))) unsigned int*)(l), 16, 0, 0)

__device__ __forceinline__ float wave_sum(float v) {
#pragma unroll
  for (int o = 32; o; o >>= 1) v += __shfl_xor(v, o);
  return v;
}
__device__ __forceinline__ float wave_max(float v) {
#pragma unroll
  for (int o = 32; o; o >>= 1) v = fmaxf(v, __shfl_xor(v, o));
  return v;
}

// ---------------- fp32 -> bf16 weight conversion (Wqkv then Wout, one launch) ----------------
__global__ __launch_bounds__(256) void cvt_all_kernel(const float* __restrict__ s1,
                                                      bf16* __restrict__ d1,
                                                      const float* __restrict__ s2,
                                                      bf16* __restrict__ d2) {
  long i = ((long)blockIdx.x * 256 + threadIdx.x) * 8;
  const float* src;
  bf16* dst;
  if (i < 50331648L) { src = s1 + i; dst = d1 + i; }
  else { src = s2 + (i - 50331648L); dst = d2 + (i - 50331648L); }
  float4 a = *(const float4*)(src);
  float4 b = *(const float4*)(src + 4);
  bf16x8 p;
  p[0] = (bf16)a.x; p[1] = (bf16)a.y; p[2] = (bf16)a.z; p[3] = (bf16)a.w;
  p[4] = (bf16)b.x; p[5] = (bf16)b.y; p[6] = (bf16)b.z; p[7] = (bf16)b.w;
  *(bf16x8*)(dst) = p;
}

// ---------------- LayerNorm(x) -> kv (bf16), kin = kv + pos (bf16) ----------------
__global__ __launch_bounds__(256) void ln_x_kernel(const float* __restrict__ x,
                                                   const float* __restrict__ w,
                                                   const float* __restrict__ bvec,
                                                   const float* __restrict__ pos,
                                                   bf16* __restrict__ kv,
                                                   bf16* __restrict__ kin) {
  const int row = blockIdx.x;          // b*256 + n
  const int n = row & (N_DIM - 1);
  const int tid = threadIdx.x, wid = tid >> 6, lane = tid & 63;
  const float* xr = x + (size_t)row * E_DIM;
  float4 v[4];
  float s1 = 0.f, s2 = 0.f;
#pragma unroll
  for (int j = 0; j < 4; ++j) {
    v[j] = *(const float4*)(xr + j * 1024 + tid * 4);
    s1 += v[j].x + v[j].y + v[j].z + v[j].w;
    s2 += v[j].x * v[j].x + v[j].y * v[j].y + v[j].z * v[j].z + v[j].w * v[j].w;
  }
  s1 = wave_sum(s1); s2 = wave_sum(s2);
  __shared__ float red[8];
  if (lane == 0) { red[wid] = s1; red[wid + 4] = s2; }
  __syncthreads();
  s1 = red[0] + red[1] + red[2] + red[3];
  s2 = red[4] + red[5] + red[6] + red[7];
  const float mean = s1 * (1.f / E_DIM);
  const float var = s2 * (1.f / E_DIM) - mean * mean;
  const float rs = rsqrtf(var + 1e-5f);
#pragma unroll
  for (int j = 0; j < 4; ++j) {
    const int idx = j * 1024 + tid * 4;
    float4 wv = *(const float4*)(w + idx);
    float4 bv = *(const float4*)(bvec + idx);
    float4 pv = *(const float4*)(pos + (size_t)n * E_DIM + idx);
    float y0 = (v[j].x - mean) * rs * wv.x + bv.x;
    float y1 = (v[j].y - mean) * rs * wv.y + bv.y;
    float y2 = (v[j].z - mean) * rs * wv.z + bv.z;
    float y3 = (v[j].w - mean) * rs * wv.w + bv.w;
    bf16x4 a; a[0] = (bf16)y0; a[1] = (bf16)y1; a[2] = (bf16)y2; a[3] = (bf16)y3;
    *(bf16x4*)(kv + (size_t)row * E_DIM + idx) = a;
    bf16x4 c; c[0] = (bf16)(y0 + pv.x); c[1] = (bf16)(y1 + pv.y);
    c[2] = (bf16)(y2 + pv.z); c[3] = (bf16)(y3 + pv.w);
    *(bf16x4*)(kin + (size_t)row * E_DIM + idx) = c;
  }
}

// ---------------- LayerNorm(query) + pos -> qin (bf16) ----------------
__global__ __launch_bounds__(256) void ln_q_kernel(const float* __restrict__ q,
                                                   const float* __restrict__ w,
                                                   const float* __restrict__ bvec,
                                                   const float* __restrict__ pos,
                                                   bf16* __restrict__ qin) {
  const int row = blockIdx.x;  // m
  const int tid = threadIdx.x, wid = tid >> 6, lane = tid & 63;
  const float* xr = q + (size_t)row * E_DIM;
  float4 v[4];
  float s1 = 0.f, s2 = 0.f;
#pragma unroll
  for (int j = 0; j < 4; ++j) {
    v[j] = *(const float4*)(xr + j * 1024 + tid * 4);
    s1 += v[j].x + v[j].y + v[j].z + v[j].w;
    s2 += v[j].x * v[j].x + v[j].y * v[j].y + v[j].z * v[j].z + v[j].w * v[j].w;
  }
  s1 = wave_sum(s1); s2 = wave_sum(s2);
  __shared__ float red[8];
  if (lane == 0) { red[wid] = s1; red[wid + 4] = s2; }
  __syncthreads();
  s1 = red[0] + red[1] + red[2] + red[3];
  s2 = red[4] + red[5] + red[6] + red[7];
  const float mean = s1 * (1.f / E_DIM);
  const float var = s2 * (1.f / E_DIM) - mean * mean;
  const float rs = rsqrtf(var + 1e-5f);
#pragma unroll
  for (int j = 0; j < 4; ++j) {
    const int idx = j * 1024 + tid * 4;
    float4 wv = *(const float4*)(w + idx);
    float4 bv = *(const float4*)(bvec + idx);
    float4 pv = *(const float4*)(pos + (size_t)row * E_DIM + idx);
    bf16x4 a;
    a[0] = (bf16)((v[j].x - mean) * rs * wv.x + bv.x + pv.x);
    a[1] = (bf16)((v[j].y - mean) * rs * wv.y + bv.y + pv.y);
    a[2] = (bf16)((v[j].z - mean) * rs * wv.z + bv.z + pv.z);
    a[3] = (bf16)((v[j].w - mean) * rs * wv.w + bv.w + pv.w);
    *(bf16x4*)(qin + (size_t)row * E_DIM + idx) = a;
  }
}

// ---------------- fused q/k/v projection GEMM, 1088 blocks ----------------
// blocks [0,512): k = kin @ Wk^T + bk           -> kp (bf16, row-major)
// blocks [512,1024): v = kv @ Wv^T + bv         -> vt (bf16, transposed (b,h,d,n))
// blocks [1024,1088): q = qin @ Wq^T + bq       -> qp (bf16, row-major)
__global__ __launch_bounds__(256, 4)
void proj_fused(const bf16* __restrict__ qin, const bf16* __restrict__ kin,
                const bf16* __restrict__ kv, const bf16* __restrict__ Wqkv,
                const float* __restrict__ bqkv, bf16* __restrict__ qp,
                bf16* __restrict__ kp, bf16* __restrict__ vt) {
  __shared__ __align__(16) bf16 As[4096];
  __shared__ __align__(16) bf16 Bs[4096];
  const int tid = threadIdx.x;
  const int wid = tid >> 6;
  const int lane = tid & 63;

  const int id = blockIdx.x;
  int role, bx, by;
  const bf16 *A, *B;
  const float* bias;
  bf16* C;
  if (id < 512) {                    // k
    role = 1; bx = id & 31; by = id >> 5;
    A = kin; B = Wqkv + 16777216; bias = bqkv + 4096; C = kp;
  } else if (id < 1024) {            // v
    role = 2; bx = (id - 512) & 31; by = (id - 512) >> 5;
    A = kv; B = Wqkv + 33554432; bias = bqkv + 8192; C = vt;
  } else {                           // q
    role = 0; bx = (id - 1024) & 31; by = (id - 1024) >> 5;
    A = qin; B = Wqkv; bias = bqkv; C = qp;
  }

  const bf16* Arow = A + (size_t)(by * 128) * E_DIM;
  const bf16* Brow = B + (size_t)(bx * 128) * E_DIM;

  const int s0 = wid * 2;
  const int srow = lane >> 2;
  const int skoff = (lane & 3) * 8;

  floatx4 acc[4][4];
#pragma unroll
  for (int i = 0; i < 4; ++i)
#pragma unroll
    for (int j = 0; j < 4; ++j) acc[i][j] = (floatx4){0.f, 0.f, 0.f, 0.f};

  const int rA = (wid >> 1) * 64 + (lane & 15);
  const int rB = (wid & 1) * 64 + (lane & 15);
  const int q16 = (lane >> 4) * 8;

  for (int kt = 0; kt < 128; ++kt) {
    const int k0 = kt << 5;
#pragma unroll
    for (int c = 0; c < 2; ++c) {
      const int s = s0 + c;
      const int row = s * 16 + srow;
      GLD_LDS(Arow + (size_t)row * E_DIM + k0 + skoff, As + s * 512);
      GLD_LDS(Brow + (size_t)row * E_DIM + k0 + skoff, Bs + s * 512);
    }
    asm volatile("s_waitcnt vmcnt(0)" ::: "memory");
    __syncthreads();

    bf16x8 af[4], bfr[4];
#pragma unroll
    for (int t = 0; t < 4; ++t) {
      af[t] = *(const bf16x8*)(As + (rA + t * 16) * 32 + q16);
      bfr[t] = *(const bf16x8*)(Bs + (rB + t * 16) * 32 + q16);
    }
#pragma unroll
    for (int tr = 0; tr < 4; ++tr)
#pragma unroll
      for (int tc = 0; tc < 4; ++tc)
        acc[tr][tc] = __builtin_amdgcn_mfma_f32_16x16x32_bf16(af[tr], bfr[tc],
                                                              acc[tr][tc], 0, 0, 0);
    __syncthreads();
  }

  const int mb = by * 128 + (wid >> 1) * 64 + (lane >> 4) * 4;
  const int nb = bx * 128 + (wid & 1) * 64 + (lane & 15);
#pragma unroll
  for (int tr = 0; tr < 4; ++tr) {
#pragma unroll
    for (int tc = 0; tc < 4; ++tc) {
      const int row0 = mb + tr * 16;
      const int col = nb + tc * 16;
      const float bb = bias[col];
      floatx4 a = acc[tr][tc];
      if (role != 2) {
#pragma unroll
        for (int r = 0; r < 4; ++r)
          C[(size_t)(row0 + r) * E_DIM + col] = (bf16)(a[r] + bb);
      } else {
        const int h = col >> 7, d = col & 127;
        const int b_ = row0 >> 8, n_ = row0 & 255;
        bf16x4 p;
#pragma unroll
        for (int r = 0; r < 4; ++r) p[r] = (bf16)(a[r] + bb);
        *(bf16x4*)(C + ((size_t)((b_ * H_DIM + h) * D_DIM + d)) * N_DIM + n_) = p;
      }
    }
  }
}

// ---------------- BT GEMM: C[m,n] = sum_k A[m,k]*B[n,k] ----------------
// MODE 2: batched z=(b,h), *scale, f32 scores
// MODE 3: batched z, bf16 -> o(b,m,h*128+d)
// MODE 5: split-K z in {0,1}, fp32 partials (out-proj)
template <int MODE>
__global__ __launch_bounds__(256, 4)
void gemm_bt(const bf16* __restrict__ Abase, const bf16* __restrict__ Bbase,
             float* __restrict__ Cf, bf16* __restrict__ Cb,
             int K, int lda, int ldb, int ldc, float scale) {
  __shared__ __align__(16) bf16 As[4096];
  __shared__ __align__(16) bf16 Bs[4096];
  const int tid = threadIdx.x;
  const int wid = tid >> 6;
  const int lane = tid & 63;

  const bf16* A = Abase;
  const bf16* B = Bbase;
  int zb = 0, zh = 0;
  if constexpr (MODE == 2) {
    int z = blockIdx.z; zb = z >> 5; zh = z & 31;
    A += zh * D_DIM;
    B += ((size_t)zb * N_DIM) * E_DIM + zh * D_DIM;
  } else if constexpr (MODE == 3) {
    int z = blockIdx.z; zb = z >> 5; zh = z & 31;
    A += (size_t)z * M_DIM * 512;   // probs: 512-ushort row stride
    B += (size_t)z * D_DIM * N_DIM; // vt batch
  } else if constexpr (MODE == 5) {
    A += blockIdx.z * 2048;         // K offset
    B += blockIdx.z * 2048;
  }

  const bf16* Arow = A + (size_t)(blockIdx.y * 128) * lda;
  const bf16* Brow = B + (size_t)(blockIdx.x * 128) * ldb;

  const int s0 = wid * 2;
  const int srow = lane >> 2;
  const int skoff = (lane & 3) * 8;

  floatx4 acc[4][4];
#pragma unroll
  for (int i = 0; i < 4; ++i)
#pragma unroll
    for (int j = 0; j < 4; ++j) acc[i][j] = (floatx4){0.f, 0.f, 0.f, 0.f};

  const int rA = (wid >> 1) * 64 + (lane & 15);
  const int rB = (wid & 1) * 64 + (lane & 15);
  const int q16 = (lane >> 4) * 8;

  const int kTiles = K >> 5;
  for (int kt = 0; kt < kTiles; ++kt) {
    const int k0 = kt << 5;
#pragma unroll
    for (int c = 0; c < 2; ++c) {
      const int s = s0 + c;
      const int row = s * 16 + srow;
      GLD_LDS(Arow + (size_t)row * lda + k0 + skoff, As + s * 512);
      GLD_LDS(Brow + (size_t)row * ldb + k0 + skoff, Bs + s * 512);
    }
    asm volatile("s_waitcnt vmcnt(0)" ::: "memory");
    __syncthreads();

    bf16x8 af[4], bfr[4];
#pragma unroll
    for (int t = 0; t < 4; ++t) {
      af[t] = *(const bf16x8*)(As + (rA + t * 16) * 32 + q16);
      bfr[t] = *(const bf16x8*)(Bs + (rB + t * 16) * 32 + q16);
    }
#pragma unroll
    for (int tr = 0; tr < 4; ++tr)
#pragma unroll
      for (int tc = 0; tc < 4; ++tc)
        acc[tr][tc] = __builtin_amdgcn_mfma_f32_16x16x32_bf16(af[tr], bfr[tc],
                                                              acc[tr][tc], 0, 0, 0);
    __syncthreads();
  }

  const int mb = blockIdx.y * 128 + (wid >> 1) * 64 + (lane >> 4) * 4;
  const int nb = blockIdx.x * 128 + (wid & 1) * 64 + (lane & 15);
#pragma unroll
  for (int tr = 0; tr < 4; ++tr) {
#pragma unroll
    for (int tc = 0; tc < 4; ++tc) {
      const int row0 = mb + tr * 16;
      const int col = nb + tc * 16;
      floatx4 a = acc[tr][tc];
      if constexpr (MODE == 2) {
#pragma unroll
        for (int r = 0; r < 4; ++r)
          Cf[(size_t)blockIdx.z * (M_DIM * N_DIM) + (size_t)(row0 + r) * ldc + col] =
              a[r] * scale;
      } else if constexpr (MODE == 3) {
        int z = blockIdx.z; int zb_ = z >> 5, zh_ = z & 31;
#pragma unroll
        for (int r = 0; r < 4; ++r)
          Cb[(size_t)zb_ * M_DIM * E_DIM + (size_t)(row0 + r) * E_DIM + zh_ * D_DIM + col] =
              (bf16)a[r];
      } else {  // MODE 5
#pragma unroll
        for (int r = 0; r < 4; ++r)
          Cf[(size_t)blockIdx.z * 8388608 + (size_t)(row0 + r) * ldc + col] = a[r];
      }
    }
  }
}

// ---------------- split-K reduce: out = p0 + p1 + bias ----------------
__global__ __launch_bounds__(256) void reduce_out_kernel(const float* __restrict__ p,
                                                         const float* __restrict__ bias,
                                                         float* __restrict__ out) {
  const size_t i = ((size_t)blockIdx.x * 256 + threadIdx.x) * 4;
  float4 a = *(const float4*)(p + i);
  float4 b = *(const float4*)(p + 8388608 + i);
  float4 bb = *(const float4*)(bias + (i & 4095));
  float4 o;
  o.x = a.x + b.x + bb.x; o.y = a.y + b.y + bb.y;
  o.z = a.z + b.z + bb.z; o.w = a.w + b.w + bb.w;
  *(float4*)(out + i) = o;
}

// ---------------- softmax over N per (b,m) for all heads + head-mean ----------------
__global__ __launch_bounds__(256) void softmax_mean_kernel(float* __restrict__ scores,
                                                           float* __restrict__ out_mean) {
  const int bm = blockIdx.x;  // b*256 + m
  const int b = bm >> 8, m = bm & 255;
  const int wid = threadIdx.x >> 6, lane = threadIdx.x & 63;
  float a0 = 0.f, a1 = 0.f, a2 = 0.f, a3 = 0.f;
  for (int j = 0; j < 8; ++j) {
    const int h = wid * 8 + j;
    float* row = scores + ((size_t)((b * H_DIM + h) * M_DIM + m)) * N_DIM;
    float4 v = *(const float4*)(row + lane * 4);
    float mx = fmaxf(fmaxf(v.x, v.y), fmaxf(v.z, v.w));
    mx = wave_max(mx);
    v.x = __expf(v.x - mx); v.y = __expf(v.y - mx);
    v.z = __expf(v.z - mx); v.w = __expf(v.w - mx);
    const float s = wave_sum(v.x + v.y + v.z + v.w);
    const float inv = 1.f / s;
    v.x *= inv; v.y *= inv; v.z *= inv; v.w *= inv;
    a0 += v.x; a1 += v.y; a2 += v.z; a3 += v.w;
    bf16x4 p; p[0] = (bf16)v.x; p[1] = (bf16)v.y; p[2] = (bf16)v.z; p[3] = (bf16)v.w;
    *(bf16x4*)((bf16*)row + lane * 4) = p;  // in-place: first 512B of the 1KB row
  }
  __shared__ float red[4][256];
  *(float4*)&red[wid][lane * 4] = make_float4(a0, a1, a2, a3);
  __syncthreads();
  if (wid == 0) {
    float4 r0 = *(float4*)&red[0][lane * 4];
    float4 r1 = *(float4*)&red[1][lane * 4];
    float4 r2 = *(float4*)&red[2][lane * 4];
    float4 r3 = *(float4*)&red[3][lane * 4];
    float4 o;
    o.x = (r0.x + r1.x + r2.x + r3.x) * (1.f / H_DIM);
    o.y = (r0.y + r1.y + r2.y + r3.y) * (1.f / H_DIM);
    o.z = (r0.z + r1.z + r2.z + r3.z) * (1.f / H_DIM);
    o.w = (r0.w + r1.w + r2.w + r3.w) * (1.f / H_DIM);
    *(float4*)(out_mean + (size_t)bm * N_DIM + lane * 4) = o;
  }
}

extern "C" void kernel_launch(void* const* d_in, const int* in_sizes, int n_in,
                              void* d_out, int out_size, void* d_ws, size_t ws_size,
                              hipStream_t stream) {
  const float* x = (const float*)d_in[0];
  const float* query = (const float*)d_in[1];
  const float* pos = (const float*)d_in[2];
  const float* ln_q_w = (const float*)d_in[3];
  const float* ln_q_b = (const float*)d_in[4];
  const float* ln_kv_w = (const float*)d_in[5];
  const float* ln_kv_b = (const float*)d_in[6];
  const float* Wqkv_f = (const float*)d_in[7];
  const float* bqkv = (const float*)d_in[8];
  const float* Wout_f = (const float*)d_in[9];
  const float* bout = (const float*)d_in[10];

  char* ws = (char*)d_ws;
  // ws layout (bytes); scores & obuf alias Wqkv (dead after proj_fused)
  bf16* Wqkv = (bf16*)(ws + 0);            // 100,663,296
  bf16* Wout = (bf16*)(ws + 100663296);    // 33,554,432
  bf16* kv   = (bf16*)(ws + 134217728);    // 16,777,216
  bf16* kin  = (bf16*)(ws + 150994944);    // 16,777,216
  bf16* qin  = (bf16*)(ws + 167772160);    //  2,097,152
  bf16* qp   = (bf16*)(ws + 169869312);    //  2,097,152
  bf16* kp   = (bf16*)(ws + 171966464);    // 16,777,216
  bf16* vt   = (bf16*)(ws + 188743680);    // 16,777,216
  float* partials = (float*)(ws + 205520896); // 67,108,864 -> end 272,629,760
  float* scores = (float*)(ws + 0);        // 67,108,864 (alias Wqkv)
  bf16* obuf = (bf16*)(ws + 67108864);     // 16,777,216 (alias Wqkv tail)

  float* out = (float*)d_out;
  float* out2 = out + (size_t)B_DIM * M_DIM * E_DIM;

  cvt_all_kernel<<<32768, 256, 0, stream>>>(Wqkv_f, Wqkv, Wout_f, Wout);
  ln_x_kernel<<<2048, 256, 0, stream>>>(x, ln_kv_w, ln_kv_b, pos, kv, kin);
  ln_q_kernel<<<256, 256, 0, stream>>>(query, ln_q_w, ln_q_b, pos, qin);

  // q/k/v projections in one 1088-block launch
  proj_fused<<<1088, 256, 0, stream>>>(qin, kin, kv, Wqkv, bqkv, qp, kp, vt);

  // scores[b,h,m,n] = q.k/sqrt(128)
  gemm_bt<2><<<dim3(2, 2, 256), 256, 0, stream>>>(qp, kp, scores, nullptr,
                                                  128, 4096, 4096, 256,
                                                  0.08838834764831845f);
  softmax_mean_kernel<<<2048, 256, 0, stream>>>(scores, out2);
  // o = probs @ v   (per (b,h): 256x128x256)
  gemm_bt<3><<<dim3(1, 2, 256), 256, 0, stream>>>((const bf16*)scores, vt,
                                                  nullptr, obuf,
                                                  256, 512, 256, 4096, 1.f);
  // out partials = o @ Wout^T, split-K=2
  gemm_bt<5><<<dim3(32, 16, 2), 256, 0, stream>>>(obuf, Wout, partials, nullptr,
                                                  2048, 4096, 4096, 4096, 1.f);
  reduce_out_kernel<<<8192, 256, 0, stream>>>(partials, bout, out);
}

// Round 3
// 788.154 us; speedup vs baseline: 1.0786x; 1.0016x over previous
//
#include <hip/hip_runtime.h>
#include <hip/hip_bf16.h>

typedef __bf16 bf16;
typedef __attribute__((ext_vector_type(8))) __bf16 bf16x8;
typedef __attribute__((ext_vector_type(4))) __bf16 bf16x4;
typedef __attribute__((ext_vector_type(4))) float floatx4;

#define E_DIM 4096
#define H_DIM 32
#define D_DIM 128
#define M_DIM 256
#define B_DIM 8
#define N_DIM 256

// async global->LDS, 16B per lane, lds dest = base + lane*16 (wave-uniform base)
#define GLD_LDS(g, l) __builtin_amdgcn_global_load_lds( \
    (const __attribute__((address_space(1))) unsigned int*)(g), \
    (__attribute__((address_space(3))) unsigned int*)(l), 16, 0, 0)

__device__ __forceinline__ float wave_sum(float v) {
#pragma unroll
  for (int o = 32; o; o >>= 1) v += __shfl_xor(v, o);
  return v;
}
__device__ __forceinline__ float wave_max(float v) {
#pragma unroll
  for (int o = 32; o; o >>= 1) v = fmaxf(v, __shfl_xor(v, o));
  return v;
}

// ---------------- double-buffered MFMA GEMM core ----------------
// As/Bs are 2*4096-element LDS buffers. One barrier per K-iteration;
// next tile's global_load_lds issues right after the barrier so the DMA
// flies during the MFMA phase and the next barrier's vmcnt drain is ~free.
__device__ __forceinline__ void gemm_core(const bf16* __restrict__ Arow,
                                          const bf16* __restrict__ Brow,
                                          int lda, int ldb, int kTiles,
                                          bf16* As, bf16* Bs,
                                          floatx4 (&acc)[4][4],
                                          int wid, int lane) {
  const int s0 = wid * 2;
  const int srow = lane >> 2;
  const int skoff = (lane & 3) * 8;
  const int rA = (wid >> 1) * 64 + (lane & 15);
  const int rB = (wid & 1) * 64 + (lane & 15);
  const int q16 = (lane >> 4) * 8;

  // prologue: stage tile 0 into buffer 0
#pragma unroll
  for (int c = 0; c < 2; ++c) {
    const int s = s0 + c;
    const int row = s * 16 + srow;
    GLD_LDS(Arow + (size_t)row * lda + skoff, As + s * 512);
    GLD_LDS(Brow + (size_t)row * ldb + skoff, Bs + s * 512);
  }

  for (int kt = 0; kt < kTiles; ++kt) {
    const int cur = (kt & 1) * 4096;
    const int nxt = 4096 - cur;
    // drains vmcnt (current buffer's DMA, in flight since last iter) and
    // lgkm (previous iter's ds_reads) for all waves.
    __syncthreads();
    if (kt + 1 < kTiles) {
      const int k0 = (kt + 1) << 5;
#pragma unroll
      for (int c = 0; c < 2; ++c) {
        const int s = s0 + c;
        const int row = s * 16 + srow;
        GLD_LDS(Arow + (size_t)row * lda + k0 + skoff, As + nxt + s * 512);
        GLD_LDS(Brow + (size_t)row * ldb + k0 + skoff, Bs + nxt + s * 512);
      }
    }
    bf16x8 af[4], bfr[4];
#pragma unroll
    for (int t = 0; t < 4; ++t) {
      af[t] = *(const bf16x8*)(As + cur + (rA + t * 16) * 32 + q16);
      bfr[t] = *(const bf16x8*)(Bs + cur + (rB + t * 16) * 32 + q16);
    }
#pragma unroll
    for (int tr = 0; tr < 4; ++tr)
#pragma unroll
      for (int tc = 0; tc < 4; ++tc)
        acc[tr][tc] = __builtin_amdgcn_mfma_f32_16x16x32_bf16(af[tr], bfr[tc],
                                                              acc[tr][tc], 0, 0, 0);
  }
}

// ---------------- fp32 -> bf16 weight conversion (Wqkv then Wout) ----------------
__global__ __launch_bounds__(256) void cvt_all_kernel(const float* __restrict__ s1,
                                                      bf16* __restrict__ d1,
                                                      const float* __restrict__ s2,
                                                      bf16* __restrict__ d2) {
  long i = ((long)blockIdx.x * 256 + threadIdx.x) * 8;
  const float* src;
  bf16* dst;
  if (i < 50331648L) { src = s1 + i; dst = d1 + i; }
  else { src = s2 + (i - 50331648L); dst = d2 + (i - 50331648L); }
  float4 a = *(const float4*)(src);
  float4 b = *(const float4*)(src + 4);
  bf16x8 p;
  p[0] = (bf16)a.x; p[1] = (bf16)a.y; p[2] = (bf16)a.z; p[3] = (bf16)a.w;
  p[4] = (bf16)b.x; p[5] = (bf16)b.y; p[6] = (bf16)b.z; p[7] = (bf16)b.w;
  *(bf16x8*)(dst) = p;
}

// ---------------- LayerNorm(x) -> kv (bf16), kin = kv + pos (bf16) ----------------
__global__ __launch_bounds__(256) void ln_x_kernel(const float* __restrict__ x,
                                                   const float* __restrict__ w,
                                                   const float* __restrict__ bvec,
                                                   const float* __restrict__ pos,
                                                   bf16* __restrict__ kv,
                                                   bf16* __restrict__ kin) {
  const int row = blockIdx.x;          // b*256 + n
  const int n = row & (N_DIM - 1);
  const int tid = threadIdx.x, wid = tid >> 6, lane = tid & 63;
  const float* xr = x + (size_t)row * E_DIM;
  float4 v[4];
  float s1 = 0.f, s2 = 0.f;
#pragma unroll
  for (int j = 0; j < 4; ++j) {
    v[j] = *(const float4*)(xr + j * 1024 + tid * 4);
    s1 += v[j].x + v[j].y + v[j].z + v[j].w;
    s2 += v[j].x * v[j].x + v[j].y * v[j].y + v[j].z * v[j].z + v[j].w * v[j].w;
  }
  s1 = wave_sum(s1); s2 = wave_sum(s2);
  __shared__ float red[8];
  if (lane == 0) { red[wid] = s1; red[wid + 4] = s2; }
  __syncthreads();
  s1 = red[0] + red[1] + red[2] + red[3];
  s2 = red[4] + red[5] + red[6] + red[7];
  const float mean = s1 * (1.f / E_DIM);
  const float var = s2 * (1.f / E_DIM) - mean * mean;
  const float rs = rsqrtf(var + 1e-5f);
#pragma unroll
  for (int j = 0; j < 4; ++j) {
    const int idx = j * 1024 + tid * 4;
    float4 wv = *(const float4*)(w + idx);
    float4 bv = *(const float4*)(bvec + idx);
    float4 pv = *(const float4*)(pos + (size_t)n * E_DIM + idx);
    float y0 = (v[j].x - mean) * rs * wv.x + bv.x;
    float y1 = (v[j].y - mean) * rs * wv.y + bv.y;
    float y2 = (v[j].z - mean) * rs * wv.z + bv.z;
    float y3 = (v[j].w - mean) * rs * wv.w + bv.w;
    bf16x4 a; a[0] = (bf16)y0; a[1] = (bf16)y1; a[2] = (bf16)y2; a[3] = (bf16)y3;
    *(bf16x4*)(kv + (size_t)row * E_DIM + idx) = a;
    bf16x4 c; c[0] = (bf16)(y0 + pv.x); c[1] = (bf16)(y1 + pv.y);
    c[2] = (bf16)(y2 + pv.z); c[3] = (bf16)(y3 + pv.w);
    *(bf16x4*)(kin + (size_t)row * E_DIM + idx) = c;
  }
}

// ---------------- LayerNorm(query) + pos -> qin (bf16) ----------------
__global__ __launch_bounds__(256) void ln_q_kernel(const float* __restrict__ q,
                                                   const float* __restrict__ w,
                                                   const float* __restrict__ bvec,
                                                   const float* __restrict__ pos,
                                                   bf16* __restrict__ qin) {
  const int row = blockIdx.x;  // m
  const int tid = threadIdx.x, wid = tid >> 6, lane = tid & 63;
  const float* xr = q + (size_t)row * E_DIM;
  float4 v[4];
  float s1 = 0.f, s2 = 0.f;
#pragma unroll
  for (int j = 0; j < 4; ++j) {
    v[j] = *(const float4*)(xr + j * 1024 + tid * 4);
    s1 += v[j].x + v[j].y + v[j].z + v[j].w;
    s2 += v[j].x * v[j].x + v[j].y * v[j].y + v[j].z * v[j].z + v[j].w * v[j].w;
  }
  s1 = wave_sum(s1); s2 = wave_sum(s2);
  __shared__ float red[8];
  if (lane == 0) { red[wid] = s1; red[wid + 4] = s2; }
  __syncthreads();
  s1 = red[0] + red[1] + red[2] + red[3];
  s2 = red[4] + red[5] + red[6] + red[7];
  const float mean = s1 * (1.f / E_DIM);
  const float var = s2 * (1.f / E_DIM) - mean * mean;
  const float rs = rsqrtf(var + 1e-5f);
#pragma unroll
  for (int j = 0; j < 4; ++j) {
    const int idx = j * 1024 + tid * 4;
    float4 wv = *(const float4*)(w + idx);
    float4 bv = *(const float4*)(bvec + idx);
    float4 pv = *(const float4*)(pos + (size_t)row * E_DIM + idx);
    bf16x4 a;
    a[0] = (bf16)((v[j].x - mean) * rs * wv.x + bv.x + pv.x);
    a[1] = (bf16)((v[j].y - mean) * rs * wv.y + bv.y + pv.y);
    a[2] = (bf16)((v[j].z - mean) * rs * wv.z + bv.z + pv.z);
    a[3] = (bf16)((v[j].w - mean) * rs * wv.w + bv.w + pv.w);
    *(bf16x4*)(qin + (size_t)row * E_DIM + idx) = a;
  }
}

// ---------------- fused q/k/v projection GEMM, 1088 blocks ----------------
__global__ __launch_bounds__(256, 2)
void proj_fused(const bf16* __restrict__ qin, const bf16* __restrict__ kin,
                const bf16* __restrict__ kv, const bf16* __restrict__ Wqkv,
                const float* __restrict__ bqkv, bf16* __restrict__ qp,
                bf16* __restrict__ kp, bf16* __restrict__ vt) {
  __shared__ __align__(16) bf16 As[8192];
  __shared__ __align__(16) bf16 Bs[8192];
  const int tid = threadIdx.x;
  const int wid = tid >> 6;
  const int lane = tid & 63;

  const int id = blockIdx.x;
  int role, bx, by;
  const bf16 *A, *B;
  const float* bias;
  bf16* C;
  if (id < 512) {                    // k
    role = 1; bx = id & 31; by = id >> 5;
    A = kin; B = Wqkv + 16777216; bias = bqkv + 4096; C = kp;
  } else if (id < 1024) {            // v
    role = 2; bx = (id - 512) & 31; by = (id - 512) >> 5;
    A = kv; B = Wqkv + 33554432; bias = bqkv + 8192; C = vt;
  } else {                           // q
    role = 0; bx = (id - 1024) & 31; by = (id - 1024) >> 5;
    A = qin; B = Wqkv; bias = bqkv; C = qp;
  }

  const bf16* Arow = A + (size_t)(by * 128) * E_DIM;
  const bf16* Brow = B + (size_t)(bx * 128) * E_DIM;

  floatx4 acc[4][4];
#pragma unroll
  for (int i = 0; i < 4; ++i)
#pragma unroll
    for (int j = 0; j < 4; ++j) acc[i][j] = (floatx4){0.f, 0.f, 0.f, 0.f};

  gemm_core(Arow, Brow, E_DIM, E_DIM, 128, As, Bs, acc, wid, lane);

  const int mb = by * 128 + (wid >> 1) * 64 + (lane >> 4) * 4;
  const int nb = bx * 128 + (wid & 1) * 64 + (lane & 15);
#pragma unroll
  for (int tr = 0; tr < 4; ++tr) {
#pragma unroll
    for (int tc = 0; tc < 4; ++tc) {
      const int row0 = mb + tr * 16;
      const int col = nb + tc * 16;
      const float bb = bias[col];
      floatx4 a = acc[tr][tc];
      if (role != 2) {
#pragma unroll
        for (int r = 0; r < 4; ++r)
          C[(size_t)(row0 + r) * E_DIM + col] = (bf16)(a[r] + bb);
      } else {
        const int h = col >> 7, d = col & 127;
        const int b_ = row0 >> 8, n_ = row0 & 255;
        bf16x4 p;
#pragma unroll
        for (int r = 0; r < 4; ++r) p[r] = (bf16)(a[r] + bb);
        *(bf16x4*)(C + ((size_t)((b_ * H_DIM + h) * D_DIM + d)) * N_DIM + n_) = p;
      }
    }
  }
}

// ---------------- BT GEMM: C[m,n] = sum_k A[m,k]*B[n,k] ----------------
// MODE 2: batched z=(b,h), *scale, f32 scores
// MODE 3: batched z, bf16 -> o(b,m,h*128+d)
// MODE 5: split-K z in {0,1}, fp32 partials (out-proj)
template <int MODE>
__global__ __launch_bounds__(256, 2)
void gemm_bt(const bf16* __restrict__ Abase, const bf16* __restrict__ Bbase,
             float* __restrict__ Cf, bf16* __restrict__ Cb,
             int K, int lda, int ldb, int ldc, float scale) {
  __shared__ __align__(16) bf16 As[8192];
  __shared__ __align__(16) bf16 Bs[8192];
  const int tid = threadIdx.x;
  const int wid = tid >> 6;
  const int lane = tid & 63;

  const bf16* A = Abase;
  const bf16* B = Bbase;
  if constexpr (MODE == 2) {
    int z = blockIdx.z; int zb = z >> 5, zh = z & 31;
    A += zh * D_DIM;
    B += ((size_t)zb * N_DIM) * E_DIM + zh * D_DIM;
  } else if constexpr (MODE == 3) {
    int z = blockIdx.z;
    A += (size_t)z * M_DIM * 512;   // probs: 512-ushort row stride
    B += (size_t)z * D_DIM * N_DIM; // vt batch
  } else if constexpr (MODE == 5) {
    A += blockIdx.z * 2048;         // K offset
    B += blockIdx.z * 2048;
  }

  const bf16* Arow = A + (size_t)(blockIdx.y * 128) * lda;
  const bf16* Brow = B + (size_t)(blockIdx.x * 128) * ldb;

  floatx4 acc[4][4];
#pragma unroll
  for (int i = 0; i < 4; ++i)
#pragma unroll
    for (int j = 0; j < 4; ++j) acc[i][j] = (floatx4){0.f, 0.f, 0.f, 0.f};

  gemm_core(Arow, Brow, lda, ldb, K >> 5, As, Bs, acc, wid, lane);

  const int mb = blockIdx.y * 128 + (wid >> 1) * 64 + (lane >> 4) * 4;
  const int nb = blockIdx.x * 128 + (wid & 1) * 64 + (lane & 15);
#pragma unroll
  for (int tr = 0; tr < 4; ++tr) {
#pragma unroll
    for (int tc = 0; tc < 4; ++tc) {
      const int row0 = mb + tr * 16;
      const int col = nb + tc * 16;
      floatx4 a = acc[tr][tc];
      if constexpr (MODE == 2) {
#pragma unroll
        for (int r = 0; r < 4; ++r)
          Cf[(size_t)blockIdx.z * (M_DIM * N_DIM) + (size_t)(row0 + r) * ldc + col] =
              a[r] * scale;
      } else if constexpr (MODE == 3) {
        int z = blockIdx.z; int zb_ = z >> 5, zh_ = z & 31;
#pragma unroll
        for (int r = 0; r < 4; ++r)
          Cb[(size_t)zb_ * M_DIM * E_DIM + (size_t)(row0 + r) * E_DIM + zh_ * D_DIM + col] =
              (bf16)a[r];
      } else {  // MODE 5
#pragma unroll
        for (int r = 0; r < 4; ++r)
          Cf[(size_t)blockIdx.z * 8388608 + (size_t)(row0 + r) * ldc + col] = a[r];
      }
    }
  }
}

// ---------------- split-K reduce: out = p0 + p1 + bias ----------------
__global__ __launch_bounds__(256) void reduce_out_kernel(const float* __restrict__ p,
                                                         const float* __restrict__ bias,
                                                         float* __restrict__ out) {
  const size_t i = ((size_t)blockIdx.x * 256 + threadIdx.x) * 4;
  float4 a = *(const float4*)(p + i);
  float4 b = *(const float4*)(p + 8388608 + i);
  float4 bb = *(const float4*)(bias + (i & 4095));
  float4 o;
  o.x = a.x + b.x + bb.x; o.y = a.y + b.y + bb.y;
  o.z = a.z + b.z + bb.z; o.w = a.w + b.w + bb.w;
  *(float4*)(out + i) = o;
}

// ---------------- softmax over N per (b,m) for all heads + head-mean ----------------
__global__ __launch_bounds__(256) void softmax_mean_kernel(float* __restrict__ scores,
                                                           float* __restrict__ out_mean) {
  const int bm = blockIdx.x;  // b*256 + m
  const int b = bm >> 8, m = bm & 255;
  const int wid = threadIdx.x >> 6, lane = threadIdx.x & 63;
  float a0 = 0.f, a1 = 0.f, a2 = 0.f, a3 = 0.f;
  for (int j = 0; j < 8; ++j) {
    const int h = wid * 8 + j;
    float* row = scores + ((size_t)((b * H_DIM + h) * M_DIM + m)) * N_DIM;
    float4 v = *(const float4*)(row + lane * 4);
    float mx = fmaxf(fmaxf(v.x, v.y), fmaxf(v.z, v.w));
    mx = wave_max(mx);
    v.x = __expf(v.x - mx); v.y = __expf(v.y - mx);
    v.z = __expf(v.z - mx); v.w = __expf(v.w - mx);
    const float s = wave_sum(v.x + v.y + v.z + v.w);
    const float inv = 1.f / s;
    v.x *= inv; v.y *= inv; v.z *= inv; v.w *= inv;
    a0 += v.x; a1 += v.y; a2 += v.z; a3 += v.w;
    bf16x4 p; p[0] = (bf16)v.x; p[1] = (bf16)v.y; p[2] = (bf16)v.z; p[3] = (bf16)v.w;
    *(bf16x4*)((bf16*)row + lane * 4) = p;  // in-place: first 512B of the 1KB row
  }
  __shared__ float red[4][256];
  *(float4*)&red[wid][lane * 4] = make_float4(a0, a1, a2, a3);
  __syncthreads();
  if (wid == 0) {
    float4 r0 = *(float4*)&red[0][lane * 4];
    float4 r1 = *(float4*)&red[1][lane * 4];
    float4 r2 = *(float4*)&red[2][lane * 4];
    float4 r3 = *(float4*)&red[3][lane * 4];
    float4 o;
    o.x = (r0.x + r1.x + r2.x + r3.x) * (1.f / H_DIM);
    o.y = (r0.y + r1.y + r2.y + r3.y) * (1.f / H_DIM);
    o.z = (r0.z + r1.z + r2.z + r3.z) * (1.f / H_DIM);
    o.w = (r0.w + r1.w + r2.w + r3.w) * (1.f / H_DIM);
    *(float4*)(out_mean + (size_t)bm * N_DIM + lane * 4) = o;
  }
}

extern "C" void kernel_launch(void* const* d_in, const int* in_sizes, int n_in,
                              void* d_out, int out_size, void* d_ws, size_t ws_size,
                              hipStream_t stream) {
  const float* x = (const float*)d_in[0];
  const float* query = (const float*)d_in[1];
  const float* pos = (const float*)d_in[2];
  const float* ln_q_w = (const float*)d_in[3];
  const float* ln_q_b = (const float*)d_in[4];
  const float* ln_kv_w = (const float*)d_in[5];
  const float* ln_kv_b = (const float*)d_in[6];
  const float* Wqkv_f = (const float*)d_in[7];
  const float* bqkv = (const float*)d_in[8];
  const float* Wout_f = (const float*)d_in[9];
  const float* bout = (const float*)d_in[10];

  char* ws = (char*)d_ws;
  bf16* Wqkv = (bf16*)(ws + 0);            // 100,663,296
  bf16* Wout = (bf16*)(ws + 100663296);    // 33,554,432
  bf16* kv   = (bf16*)(ws + 134217728);    // 16,777,216
  bf16* kin  = (bf16*)(ws + 150994944);    // 16,777,216
  bf16* qin  = (bf16*)(ws + 167772160);    //  2,097,152
  bf16* qp   = (bf16*)(ws + 169869312);    //  2,097,152
  bf16* kp   = (bf16*)(ws + 171966464);    // 16,777,216
  bf16* vt   = (bf16*)(ws + 188743680);    // 16,777,216
  float* partials = (float*)(ws + 205520896); // 67,108,864 -> end 272,629,760
  float* scores = (float*)(ws + 0);        // 67,108,864 (alias Wqkv)
  bf16* obuf = (bf16*)(ws + 67108864);     // 16,777,216 (alias Wqkv tail)

  float* out = (float*)d_out;
  float* out2 = out + (size_t)B_DIM * M_DIM * E_DIM;

  cvt_all_kernel<<<32768, 256, 0, stream>>>(Wqkv_f, Wqkv, Wout_f, Wout);
  ln_x_kernel<<<2048, 256, 0, stream>>>(x, ln_kv_w, ln_kv_b, pos, kv, kin);
  ln_q_kernel<<<256, 256, 0, stream>>>(query, ln_q_w, ln_q_b, pos, qin);

  // q/k/v projections in one 1088-block launch
  proj_fused<<<1088, 256, 0, stream>>>(qin, kin, kv, Wqkv, bqkv, qp, kp, vt);

  // scores[b,h,m,n] = q.k/sqrt(128)
  gemm_bt<2><<<dim3(2, 2, 256), 256, 0, stream>>>(qp, kp, scores, nullptr,
                                                  128, 4096, 4096, 256,
                                                  0.08838834764831845f);
  softmax_mean_kernel<<<2048, 256, 0, stream>>>(scores, out2);
  // o = probs @ v   (per (b,h): 256x128x256)
  gemm_bt<3><<<dim3(1, 2, 256), 256, 0, stream>>>((const bf16*)scores, vt,
                                                  nullptr, obuf,
                                                  256, 512, 256, 4096, 1.f);
  // out partials = o @ Wout^T, split-K=2
  gemm_bt<5><<<dim3(32, 16, 2), 256, 0, stream>>>(obuf, Wout, partials, nullptr,
                                                  2048, 4096, 4096, 4096, 1.f);
  reduce_out_kernel<<<8192, 256, 0, stream>>>(partials, bout, out);
}